// Round 28
// baseline (366.442 us; speedup 1.0000x reference)
//
#include <hip/hip_runtime.h>
#include <cstddef>

#define BB   8
#define NN   2048
#define CIN  64
#define COUT 64
#define KK   20
#define KSS  20
#define C2   128   // 2*CIN
#define NJ8  (C2 * KSS / 8)   // 320 8-wide f16 rows of the conv matrix
#define PPB  4                 // points per block (point_kernel)
#define JQ8  (NJ8 / PPB)       // 80 j8-rows per wave in cooperative conv
#define NC   24                // fp32 candidate count for knn refine

typedef _Float16 h2t __attribute__((ext_vector_type(2)));

__device__ __forceinline__ unsigned pk2(float a, float b) {
    unsigned short ua = __builtin_bit_cast(unsigned short, (_Float16)a);
    unsigned short ub = __builtin_bit_cast(unsigned short, (_Float16)b);
    return (unsigned)ua | ((unsigned)ub << 16);
}
__device__ __forceinline__ h2t bc2(unsigned u) {
    return __builtin_bit_cast(h2t, u);
}

// ---------------------------------------------------------------------------
// Prep: wTh[j8*64 + t] = 8 f16 of conv_w[t][8*j8..+7]; mowT[c*64+o] = mow[o][c]
// ---------------------------------------------------------------------------
__global__ __launch_bounds__(256) void prep_kernel(
    const float* __restrict__ cw, const float* __restrict__ mw,
    uint4* __restrict__ wTh, float* __restrict__ mowT)
{
    int i = blockIdx.x * 256 + threadIdx.x;
    if (i < NJ8 * COUT) {
        int j8 = i >> 6, t = i & 63;
        const float* s = cw + (size_t)t * (C2 * KSS) + j8 * 8;
        uint4 o;
        o.x = pk2(s[0], s[1]);
        o.y = pk2(s[2], s[3]);
        o.z = pk2(s[4], s[5]);
        o.w = pk2(s[6], s[7]);
        wTh[i] = o;
    }
    if (i < COUT * CIN) {
        int o = i >> 6, c = i & 63;
        mowT[c * COUT + o] = mw[o * CIN + c];
    }
}

// ---------------------------------------------------------------------------
// KNN (standalone, proven v3): fp32 packed-u64 selection of 24 candidates
// (top-3 lane cache + killmask) then fp64 exact re-rank via 32-lane bitonic
// sort. Membership fp64-exact, ties lowest-index. One wave per query.
// Zero LDS -> high occupancy; own VGPR allocation (d2r lives only here).
// ---------------------------------------------------------------------------
__global__ __launch_bounds__(64) void knn_kernel(
    const float* __restrict__ x, unsigned short* __restrict__ idx_out)
{
    const unsigned long long SENT = 0xFFFFFFFFFFFFFFFFull;
    const int t = threadIdx.x;
    const int p = blockIdx.x;
    const int b = p >> 11;
    const int n = p & (NN - 1);

    const float* xb0 = x + (size_t)(b * 3 + 0) * NN;
    const float* xb1 = x + (size_t)(b * 3 + 1) * NN;
    const float* xb2 = x + (size_t)(b * 3 + 2) * NN;

    const float qx = xb0[n], qy = xb1[n], qz = xb2[n];

    float d2r[32];
#pragma unroll
    for (int j = 0; j < 32; ++j) {
        int m = t + 64 * j;
        float dx = xb0[m] - qx;
        float dy = xb1[m] - qy;
        float dz = xb2[m] - qz;
        d2r[j] = dx * dx + dy * dy + dz * dz;
    }

    unsigned long long c0 = SENT, c1 = SENT, c2 = SENT;
#pragma unroll
    for (int j = 0; j < 32; ++j) {
        unsigned long long pk =
            ((unsigned long long)__float_as_uint(d2r[j]) << 32)
            | (unsigned)(t + 64 * j);
        if (pk < c0)      { c2 = c1; c1 = c0; c0 = pk; }
        else if (pk < c1) { c2 = c1; c1 = pk; }
        else if (pk < c2) { c2 = pk; }
    }

    unsigned killmask = 0u;
    unsigned long long mypk = SENT;
    for (int k = 0; k < NC; ++k) {
        unsigned long long bp = c0;
#pragma unroll
        for (int off = 32; off > 0; off >>= 1) {
            unsigned long long op_ = __shfl_down(bp, off);
            if (op_ < bp) bp = op_;
        }
        bp = __shfl(bp, 0);
        if (t == k) mypk = bp;
        if (c0 == bp) {
            killmask |= 1u << ((unsigned)(bp & 0xFFFFFFFFull) >> 6);
            c0 = c1; c1 = c2; c2 = SENT;
            if (c0 == SENT) {
#pragma unroll
                for (int j = 0; j < 32; ++j) {
                    if (!(killmask & (1u << j))) {
                        unsigned long long pk =
                            ((unsigned long long)__float_as_uint(d2r[j]) << 32)
                            | (unsigned)(t + 64 * j);
                        if (pk < c0)      { c2 = c1; c1 = c0; c0 = pk; }
                        else if (pk < c1) { c2 = c1; c1 = pk; }
                        else if (pk < c2) { c2 = pk; }
                    }
                }
            }
        }
    }

    double dd = 1e300;
    int ci = 0x7fffffff;
    if (t < NC) {
        ci = (int)(mypk & 0xFFFFFFFFull);
        double dx = (double)xb0[ci] - (double)qx;
        double dy = (double)xb1[ci] - (double)qy;
        double dz = (double)xb2[ci] - (double)qz;
        dd = dx * dx + dy * dy + dz * dz;
    }
    unsigned long long db = __double_as_longlong(dd);
#pragma unroll
    for (int size = 2; size <= 32; size <<= 1) {
#pragma unroll
        for (int stride = size >> 1; stride > 0; stride >>= 1) {
            unsigned long long odb = __shfl_xor(db, stride);
            int oci = __shfl_xor(ci, stride);
            bool up = ((t & size) == 0);
            bool takemin = (((t & stride) == 0) == up);
            bool oless = (odb < db) || (odb == db && oci < ci);
            if (takemin == oless) { db = odb; ci = oci; }
        }
    }
    if (t < KK) idx_out[(size_t)p * KK + t] = (unsigned short)ci;
}

// ---------------------------------------------------------------------------
// Per-point pipeline WITHOUT KNN (reads idx). Wave-local phases barrier-free;
// 2 barriers total. Plain launch_bounds(256): without d2r live the natural
// VGPR demand (~70) lets LDS (30.2 KB) set occupancy at ~5 blocks/CU.
// (256,4)/(256,5) hints are poison: allocator clamps+spills (r23/r26).
// ---------------------------------------------------------------------------
__global__ __launch_bounds__(256) void point_kernel(
    const float* __restrict__ x,
    const float* __restrict__ feature,
    const float* __restrict__ kern,
    const float* __restrict__ pad,
    const float* __restrict__ mlp_w,
    const float* __restrict__ mlp_b,
    const uint4* __restrict__ wTh,
    const float* __restrict__ conv_b,
    const float* __restrict__ mowT,
    const float* __restrict__ mob,
    const unsigned short* __restrict__ idx,
    float* __restrict__ out)
{
    __shared__ __align__(16) _Float16 agg_h[PPB][C2 * KSS];  // 20480 B
    __shared__ __align__(16) float u_s[PPB * KK * KSS];      // 6400 B (perm|red)
    __shared__ float xr_s[PPB][KK][3];
    __shared__ float xd_s[PPB][KK];
    __shared__ float xrep_s[PPB][3];
    __shared__ float colden_s[PPB][KSS];
    __shared__ float fcol_s[PPB][CIN];
    __shared__ int   nid_s[PPB][KK];

    float (*perm_s)[KK][KSS] = (float (*)[KK][KSS])u_s;
    float (*red_s)[PPB][64]  = (float (*)[PPB][64])u_s;

    const int tid  = threadIdx.x;
    const int w    = tid >> 6;
    const int lane = tid & 63;
    const int p    = blockIdx.x * PPB + w;
    const int b    = p >> 11;
    const int n    = p & (NN - 1);

    const float* xb0 = x + (size_t)(b * 3 + 0) * NN;
    const float* xb1 = x + (size_t)(b * 3 + 1) * NN;
    const float* xb2 = x + (size_t)(b * 3 + 2) * NN;

    // ======= per-point pipeline: all wave-local, NO barriers needed =======
    if (lane < KK) nid_s[w][lane] = (int)idx[(size_t)p * KK + lane];
    fcol_s[w][lane] = feature[(size_t)(b * CIN + lane) * NN + n];

    if (lane == 0) {
        int m0 = nid_s[w][0];
        xrep_s[w][0] = xb0[m0]; xrep_s[w][1] = xb1[m0]; xrep_s[w][2] = xb2[m0];
    }
    if (lane < KK) {
        int m = nid_s[w][lane];
        float rx = xb0[m] - xrep_s[w][0];
        float ry = xb1[m] - xrep_s[w][1];
        float rz = xb2[m] - xrep_s[w][2];
        xr_s[w][lane][0] = rx; xr_s[w][lane][1] = ry; xr_s[w][lane][2] = rz;
        xd_s[w][lane] = sqrtf(rx * rx + ry * ry + rz * rz + 1e-12f);
    }

    // ---- perm: relu -> colnorm -> square -> colnorm -> >0.1 (wave-local) --
    for (int e = lane; e < KK * KSS; e += 64) {
        int k = e / KSS, m = e % KSS;
        float v = xr_s[w][k][0] * kern[0 * KSS + m]
                + xr_s[w][k][1] * kern[1 * KSS + m]
                + xr_s[w][k][2] * kern[2 * KSS + m]
                + pad[k * KSS + m];
        perm_s[w][k][m] = v > 0.0f ? v : 0.0f;
    }
    if (lane < KSS) {
        float s = 0.0f;
        for (int k = 0; k < KK; ++k) s += perm_s[w][k][lane];
        colden_s[w][lane] = s + 1e-6f;
    }
    for (int e = lane; e < KK * KSS; e += 64) {
        int k = e / KSS, m = e % KSS;
        float v = perm_s[w][k][m] / colden_s[w][m];
        perm_s[w][k][m] = v * v;
    }
    if (lane < KSS) {
        float s = 0.0f;
        for (int k = 0; k < KK; ++k) s += perm_s[w][k][lane];
        colden_s[w][lane] = s + 1e-6f;
    }
    for (int e = lane; e < KK * KSS; e += 64) {
        int k = e / KSS, m = e % KSS;
        float v = perm_s[w][k][m] / colden_s[w][m];
        perm_s[w][k][m] = v > 0.1f ? v : 0.0f;
    }

    // ---- feats in registers (wave-local) ----
    float fg[KK], fm[KK];
#pragma unroll
    for (int k = 0; k < KK; ++k)
        fg[k] = feature[(size_t)(b * CIN + lane) * NN + nid_s[w][k]];
    {
        float w0 = mlp_w[lane * 7 + 0], w1 = mlp_w[lane * 7 + 1];
        float w2 = mlp_w[lane * 7 + 2], w3 = mlp_w[lane * 7 + 3];
        float w4 = mlp_w[lane * 7 + 4], w5 = mlp_w[lane * 7 + 5];
        float w6 = mlp_w[lane * 7 + 6];
        float bias = mlp_b[lane];
#pragma unroll
        for (int k = 0; k < KK; ++k) {
            fm[k] = xrep_s[w][0] * w0 + xrep_s[w][1] * w1 + xrep_s[w][2] * w2
                  + xr_s[w][k][0] * w3 + xr_s[w][k][1] * w4 + xr_s[w][k][2] * w5
                  + xd_s[w][k] * w6 + bias;
        }
    }

    // ---- agg rows c=lane, c=64+lane; f16 store (wave-local, r25 form) ----
#pragma unroll
    for (int m = 0; m < KSS; ++m) {
        float s = 0.0f, s2 = 0.0f;
#pragma unroll
        for (int k = 0; k < KK; ++k) {
            float pv = perm_s[w][k][m];
            s  += fg[k] * pv;
            s2 += fm[k] * pv;
        }
        agg_h[w][lane * KSS + m]         = (_Float16)s;
        agg_h[w][(CIN + lane) * KSS + m] = (_Float16)s2;
    }
    __syncthreads();   // BARRIER 1: cross-wave agg_h; perm_s -> red_s handoff

    // ---- cooperative conv: f16 dot2, wave w -> j8 in [w*JQ8,(w+1)*JQ8) ----
    {
        float pa0 = 0.0f, pa1 = 0.0f, pa2 = 0.0f, pa3 = 0.0f;
        const uint4* wp = wTh + lane;
        const int j8lo = w * JQ8, j8hi = j8lo + JQ8;
#pragma unroll 2
        for (int j8 = j8lo; j8 < j8hi; ++j8) {
            uint4 wv = wp[(size_t)j8 * 64];                     // 8 f16 weights
            uint4 a0 = *(const uint4*)(&agg_h[0][j8 * 8]);      // broadcast
            uint4 a1 = *(const uint4*)(&agg_h[1][j8 * 8]);
            uint4 a2 = *(const uint4*)(&agg_h[2][j8 * 8]);
            uint4 a3 = *(const uint4*)(&agg_h[3][j8 * 8]);
            h2t w0 = bc2(wv.x), w1 = bc2(wv.y), w2 = bc2(wv.z), w3 = bc2(wv.w);
            pa0 = __builtin_amdgcn_fdot2(w0, bc2(a0.x), pa0, false);
            pa0 = __builtin_amdgcn_fdot2(w1, bc2(a0.y), pa0, false);
            pa0 = __builtin_amdgcn_fdot2(w2, bc2(a0.z), pa0, false);
            pa0 = __builtin_amdgcn_fdot2(w3, bc2(a0.w), pa0, false);
            pa1 = __builtin_amdgcn_fdot2(w0, bc2(a1.x), pa1, false);
            pa1 = __builtin_amdgcn_fdot2(w1, bc2(a1.y), pa1, false);
            pa1 = __builtin_amdgcn_fdot2(w2, bc2(a1.z), pa1, false);
            pa1 = __builtin_amdgcn_fdot2(w3, bc2(a1.w), pa1, false);
            pa2 = __builtin_amdgcn_fdot2(w0, bc2(a2.x), pa2, false);
            pa2 = __builtin_amdgcn_fdot2(w1, bc2(a2.y), pa2, false);
            pa2 = __builtin_amdgcn_fdot2(w2, bc2(a2.z), pa2, false);
            pa2 = __builtin_amdgcn_fdot2(w3, bc2(a2.w), pa2, false);
            pa3 = __builtin_amdgcn_fdot2(w0, bc2(a3.x), pa3, false);
            pa3 = __builtin_amdgcn_fdot2(w1, bc2(a3.y), pa3, false);
            pa3 = __builtin_amdgcn_fdot2(w2, bc2(a3.z), pa3, false);
            pa3 = __builtin_amdgcn_fdot2(w3, bc2(a3.w), pa3, false);
        }
        red_s[0][w][lane] = pa0;
        red_s[1][w][lane] = pa1;
        red_s[2][w][lane] = pa2;
        red_s[3][w][lane] = pa3;
    }
    __syncthreads();   // BARRIER 2: cross-wave red_s

    // ---- wave w finalizes point w ----
    {
        float acc = conv_b[lane]
                  + ((red_s[w][0][lane] + red_s[w][1][lane])
                   + (red_s[w][2][lane] + red_s[w][3][lane]));
        for (int c = 0; c < CIN; ++c)
            acc += fcol_s[w][c] * mowT[c * COUT + lane];
        acc += mob[lane];
        out[(size_t)(b * COUT + lane) * NN + n] = acc;
    }
}

// ---------------------------------------------------------------------------
// BatchNorm per channel over (B,N), fp32 in-place. 64 blocks x 256.
// ---------------------------------------------------------------------------
__global__ __launch_bounds__(256) void bn_kernel(
    float* __restrict__ out,
    const float* __restrict__ gamma,
    const float* __restrict__ beta)
{
    const int o = blockIdx.x;
    __shared__ float s1[256], s2[256];
    __shared__ float mean_s, inv_s;

    float a = 0.0f, q = 0.0f;
    for (int i = threadIdx.x; i < BB * NN; i += 256) {
        int b = i >> 11, n = i & (NN - 1);
        float v = out[(size_t)(b * COUT + o) * NN + n];
        a += v; q += v * v;
    }
    s1[threadIdx.x] = a; s2[threadIdx.x] = q;
    __syncthreads();
    for (int s = 128; s > 0; s >>= 1) {
        if (threadIdx.x < s) {
            s1[threadIdx.x] += s1[threadIdx.x + s];
            s2[threadIdx.x] += s2[threadIdx.x + s];
        }
        __syncthreads();
    }
    if (threadIdx.x == 0) {
        const float M = (float)(BB * NN);
        float mean = s1[0] / M;
        float var  = s2[0] / M - mean * mean;
        if (var < 0.0f) var = 0.0f;
        mean_s = mean;
        inv_s  = 1.0f / sqrtf(var + 1e-5f);
    }
    __syncthreads();
    const float mean = mean_s, inv = inv_s;
    const float g = gamma[o], be = beta[o];
    for (int i = threadIdx.x; i < BB * NN; i += 256) {
        int b = i >> 11, n = i & (NN - 1);
        size_t ad = (size_t)(b * COUT + o) * NN + n;
        out[ad] = (out[ad] - mean) * inv * g + be;
    }
}

// ---------------------------------------------------------------------------
extern "C" void kernel_launch(void* const* d_in, const int* in_sizes, int n_in,
                              void* d_out, int out_size, void* d_ws, size_t ws_size,
                              hipStream_t stream)
{
    const float* x       = (const float*)d_in[0];
    const float* feature = (const float*)d_in[1];
    const float* kern    = (const float*)d_in[2];
    const float* pad     = (const float*)d_in[3];
    const float* mlp_w   = (const float*)d_in[4];
    const float* mlp_b   = (const float*)d_in[5];
    const float* conv_w  = (const float*)d_in[6];
    const float* conv_b  = (const float*)d_in[7];
    const float* mow     = (const float*)d_in[8];
    const float* mob     = (const float*)d_in[9];
    const float* gamma   = (const float*)d_in[10];
    const float* beta    = (const float*)d_in[11];

    char* wsp = (char*)d_ws;
    uint4*          wTh     = (uint4*)wsp;                       // 327680 B
    float*          mowT    = (float*)(wsp + 327680);            //  16384 B
    unsigned short* idx_buf = (unsigned short*)(wsp + 344064);   // 655360 B

    float* out = (float*)d_out;

    prep_kernel<<<(NJ8 * COUT + 255) / 256, 256, 0, stream>>>(conv_w, mow, wTh, mowT);
    knn_kernel<<<BB * NN, 64, 0, stream>>>(x, idx_buf);
    point_kernel<<<BB * NN / PPB, 256, 0, stream>>>(x, feature, kern, pad,
                                                    mlp_w, mlp_b, wTh, conv_b,
                                                    mowT, mob, idx_buf, out);
    bn_kernel<<<COUT, 256, 0, stream>>>(out, gamma, beta);
}

// Round 29
// 350.879 us; speedup vs baseline: 1.0444x; 1.0444x over previous
//
#include <hip/hip_runtime.h>
#include <cstddef>

#define BB   8
#define NN   2048
#define CIN  64
#define COUT 64
#define KK   20
#define KSS  20
#define C2   128   // 2*CIN
#define NJ8  (C2 * KSS / 8)   // 320 8-wide f16 rows of the conv matrix
#define PPB  4                 // points per block
#define JQ8  (NJ8 / PPB)       // 80 j8-rows per wave in cooperative conv
#define NC   24                // fp32 candidate count for knn refine

typedef _Float16 h2t __attribute__((ext_vector_type(2)));

__device__ __forceinline__ unsigned pk2(float a, float b) {
    unsigned short ua = __builtin_bit_cast(unsigned short, (_Float16)a);
    unsigned short ub = __builtin_bit_cast(unsigned short, (_Float16)b);
    return (unsigned)ua | ((unsigned)ub << 16);
}
__device__ __forceinline__ h2t bc2(unsigned u) {
    return __builtin_bit_cast(h2t, u);
}

// ---------------------------------------------------------------------------
// Prep: wTh[j8*64 + t] = 8 f16 of conv_w[t][8*j8..+7]; mowT[c*64+o] = mow[o][c]
// ---------------------------------------------------------------------------
__global__ __launch_bounds__(256) void prep_kernel(
    const float* __restrict__ cw, const float* __restrict__ mw,
    uint4* __restrict__ wTh, float* __restrict__ mowT)
{
    int i = blockIdx.x * 256 + threadIdx.x;
    if (i < NJ8 * COUT) {
        int j8 = i >> 6, t = i & 63;
        const float* s = cw + (size_t)t * (C2 * KSS) + j8 * 8;
        uint4 o;
        o.x = pk2(s[0], s[1]);
        o.y = pk2(s[2], s[3]);
        o.z = pk2(s[4], s[5]);
        o.w = pk2(s[6], s[7]);
        wTh[i] = o;
    }
    if (i < COUT * CIN) {
        int o = i >> 6, c = i & 63;
        mowT[c * COUT + o] = mw[o * CIN + c];
    }
}

// ---------------------------------------------------------------------------
// FUSED kernel (best-measured r25 config + xor-butterfly min-reduce).
// Wave-local phases barrier-free; 2 barriers total. launch_bounds(256,3):
// proven no-spill (84 VGPR); (256,4)/(256,5) spill catastrophically.
// ---------------------------------------------------------------------------
__global__ __launch_bounds__(256, 3) void point_kernel(
    const float* __restrict__ x,
    const float* __restrict__ feature,
    const float* __restrict__ kern,
    const float* __restrict__ pad,
    const float* __restrict__ mlp_w,
    const float* __restrict__ mlp_b,
    const uint4* __restrict__ wTh,
    const float* __restrict__ conv_b,
    const float* __restrict__ mowT,
    const float* __restrict__ mob,
    float* __restrict__ out)
{
    __shared__ __align__(16) _Float16 agg_h[PPB][C2 * KSS];  // 20480 B
    __shared__ __align__(16) float u_s[PPB * KK * KSS];      // 6400 B (perm|red)
    __shared__ float xr_s[PPB][KK][3];
    __shared__ float xd_s[PPB][KK];
    __shared__ float xrep_s[PPB][3];
    __shared__ float colden_s[PPB][KSS];
    __shared__ float fcol_s[PPB][CIN];
    __shared__ int   nid_s[PPB][KK];

    float (*perm_s)[KK][KSS] = (float (*)[KK][KSS])u_s;
    float (*red_s)[PPB][64]  = (float (*)[PPB][64])u_s;

    const int tid  = threadIdx.x;
    const int w    = tid >> 6;
    const int lane = tid & 63;
    const int p    = blockIdx.x * PPB + w;
    const int b    = p >> 11;
    const int n    = p & (NN - 1);

    const float* xb0 = x + (size_t)(b * 3 + 0) * NN;
    const float* xb1 = x + (size_t)(b * 3 + 1) * NN;
    const float* xb2 = x + (size_t)(b * 3 + 2) * NN;

    // ================= phase 0: KNN (wave-local, verified v3) =============
    {
        const unsigned long long SENT = 0xFFFFFFFFFFFFFFFFull;
        const float qx = xb0[n], qy = xb1[n], qz = xb2[n];

        float d2r[32];
#pragma unroll
        for (int j = 0; j < 32; ++j) {
            int m = lane + 64 * j;
            float dx = xb0[m] - qx;
            float dy = xb1[m] - qy;
            float dz = xb2[m] - qz;
            d2r[j] = dx * dx + dy * dy + dz * dz;
        }

        unsigned long long c0 = SENT, c1 = SENT, c2 = SENT;
#pragma unroll
        for (int j = 0; j < 32; ++j) {
            unsigned long long pk =
                ((unsigned long long)__float_as_uint(d2r[j]) << 32)
                | (unsigned)(lane + 64 * j);
            if (pk < c0)      { c2 = c1; c1 = c0; c0 = pk; }
            else if (pk < c1) { c2 = c1; c1 = pk; }
            else if (pk < c2) { c2 = pk; }
        }

        unsigned killmask = 0u;
        unsigned long long mypk = SENT;
        for (int k = 0; k < NC; ++k) {
            // xor-butterfly min: all lanes converge to global min (no bcast)
            unsigned long long bp = c0;
#pragma unroll
            for (int off = 32; off > 0; off >>= 1) {
                unsigned long long op_ = __shfl_xor(bp, off);
                if (op_ < bp) bp = op_;
            }
            if (lane == k) mypk = bp;
            if (c0 == bp) {                       // unique owner lane
                killmask |= 1u << ((unsigned)(bp & 0xFFFFFFFFull) >> 6);
                c0 = c1; c1 = c2; c2 = SENT;
                if (c0 == SENT) {                 // rare rescan
#pragma unroll
                    for (int j = 0; j < 32; ++j) {
                        if (!(killmask & (1u << j))) {
                            unsigned long long pk =
                                ((unsigned long long)__float_as_uint(d2r[j]) << 32)
                                | (unsigned)(lane + 64 * j);
                            if (pk < c0)      { c2 = c1; c1 = c0; c0 = pk; }
                            else if (pk < c1) { c2 = c1; c1 = pk; }
                            else if (pk < c2) { c2 = pk; }
                        }
                    }
                }
            }
        }

        double dd = 1e300;
        int ci = 0x7fffffff;
        if (lane < NC) {
            ci = (int)(mypk & 0xFFFFFFFFull);
            double dx = (double)xb0[ci] - (double)qx;
            double dy = (double)xb1[ci] - (double)qy;
            double dz = (double)xb2[ci] - (double)qz;
            dd = dx * dx + dy * dy + dz * dz;
        }
        unsigned long long db = __double_as_longlong(dd);
#pragma unroll
        for (int size = 2; size <= 32; size <<= 1) {
#pragma unroll
            for (int stride = size >> 1; stride > 0; stride >>= 1) {
                unsigned long long odb = __shfl_xor(db, stride);
                int oci = __shfl_xor(ci, stride);
                bool up = ((lane & size) == 0);
                bool takemin = (((lane & stride) == 0) == up);
                bool oless = (odb < db) || (odb == db && oci < ci);
                if (takemin == oless) { db = odb; ci = oci; }
            }
        }
        if (lane < KK) nid_s[w][lane] = ci;     // same-wave producer/consumer
    }

    // ======= per-point pipeline: all wave-local, NO barriers needed =======
    fcol_s[w][lane] = feature[(size_t)(b * CIN + lane) * NN + n];

    if (lane == 0) {
        int m0 = nid_s[w][0];
        xrep_s[w][0] = xb0[m0]; xrep_s[w][1] = xb1[m0]; xrep_s[w][2] = xb2[m0];
    }
    if (lane < KK) {
        int m = nid_s[w][lane];
        float rx = xb0[m] - xrep_s[w][0];
        float ry = xb1[m] - xrep_s[w][1];
        float rz = xb2[m] - xrep_s[w][2];
        xr_s[w][lane][0] = rx; xr_s[w][lane][1] = ry; xr_s[w][lane][2] = rz;
        xd_s[w][lane] = sqrtf(rx * rx + ry * ry + rz * rz + 1e-12f);
    }

    // ---- perm: relu -> colnorm -> square -> colnorm -> >0.1 (wave-local) --
    for (int e = lane; e < KK * KSS; e += 64) {
        int k = e / KSS, m = e % KSS;
        float v = xr_s[w][k][0] * kern[0 * KSS + m]
                + xr_s[w][k][1] * kern[1 * KSS + m]
                + xr_s[w][k][2] * kern[2 * KSS + m]
                + pad[k * KSS + m];
        perm_s[w][k][m] = v > 0.0f ? v : 0.0f;
    }
    if (lane < KSS) {
        float s = 0.0f;
        for (int k = 0; k < KK; ++k) s += perm_s[w][k][lane];
        colden_s[w][lane] = s + 1e-6f;
    }
    for (int e = lane; e < KK * KSS; e += 64) {
        int k = e / KSS, m = e % KSS;
        float v = perm_s[w][k][m] / colden_s[w][m];
        perm_s[w][k][m] = v * v;
    }
    if (lane < KSS) {
        float s = 0.0f;
        for (int k = 0; k < KK; ++k) s += perm_s[w][k][lane];
        colden_s[w][lane] = s + 1e-6f;
    }
    for (int e = lane; e < KK * KSS; e += 64) {
        int k = e / KSS, m = e % KSS;
        float v = perm_s[w][k][m] / colden_s[w][m];
        perm_s[w][k][m] = v > 0.1f ? v : 0.0f;
    }

    // ---- feats in registers (wave-local) ----
    float fg[KK], fm[KK];
#pragma unroll
    for (int k = 0; k < KK; ++k)
        fg[k] = feature[(size_t)(b * CIN + lane) * NN + nid_s[w][k]];
    {
        float w0 = mlp_w[lane * 7 + 0], w1 = mlp_w[lane * 7 + 1];
        float w2 = mlp_w[lane * 7 + 2], w3 = mlp_w[lane * 7 + 3];
        float w4 = mlp_w[lane * 7 + 4], w5 = mlp_w[lane * 7 + 5];
        float w6 = mlp_w[lane * 7 + 6];
        float bias = mlp_b[lane];
#pragma unroll
        for (int k = 0; k < KK; ++k) {
            fm[k] = xrep_s[w][0] * w0 + xrep_s[w][1] * w1 + xrep_s[w][2] * w2
                  + xr_s[w][k][0] * w3 + xr_s[w][k][1] * w4 + xr_s[w][k][2] * w5
                  + xd_s[w][k] * w6 + bias;
        }
    }

    // ---- agg rows c=lane, c=64+lane; f16 store (wave-local, scalar form) --
#pragma unroll
    for (int m = 0; m < KSS; ++m) {
        float s = 0.0f, s2 = 0.0f;
#pragma unroll
        for (int k = 0; k < KK; ++k) {
            float pv = perm_s[w][k][m];
            s  += fg[k] * pv;
            s2 += fm[k] * pv;
        }
        agg_h[w][lane * KSS + m]         = (_Float16)s;
        agg_h[w][(CIN + lane) * KSS + m] = (_Float16)s2;
    }
    __syncthreads();   // BARRIER 1: cross-wave agg_h; perm_s -> red_s handoff

    // ---- cooperative conv: f16 dot2, wave w -> j8 in [w*JQ8,(w+1)*JQ8) ----
    {
        float pa0 = 0.0f, pa1 = 0.0f, pa2 = 0.0f, pa3 = 0.0f;
        const uint4* wp = wTh + lane;
        const int j8lo = w * JQ8, j8hi = j8lo + JQ8;
#pragma unroll 2
        for (int j8 = j8lo; j8 < j8hi; ++j8) {
            uint4 wv = wp[(size_t)j8 * 64];                     // 8 f16 weights
            uint4 a0 = *(const uint4*)(&agg_h[0][j8 * 8]);      // broadcast
            uint4 a1 = *(const uint4*)(&agg_h[1][j8 * 8]);
            uint4 a2 = *(const uint4*)(&agg_h[2][j8 * 8]);
            uint4 a3 = *(const uint4*)(&agg_h[3][j8 * 8]);
            h2t w0 = bc2(wv.x), w1 = bc2(wv.y), w2 = bc2(wv.z), w3 = bc2(wv.w);
            pa0 = __builtin_amdgcn_fdot2(w0, bc2(a0.x), pa0, false);
            pa0 = __builtin_amdgcn_fdot2(w1, bc2(a0.y), pa0, false);
            pa0 = __builtin_amdgcn_fdot2(w2, bc2(a0.z), pa0, false);
            pa0 = __builtin_amdgcn_fdot2(w3, bc2(a0.w), pa0, false);
            pa1 = __builtin_amdgcn_fdot2(w0, bc2(a1.x), pa1, false);
            pa1 = __builtin_amdgcn_fdot2(w1, bc2(a1.y), pa1, false);
            pa1 = __builtin_amdgcn_fdot2(w2, bc2(a1.z), pa1, false);
            pa1 = __builtin_amdgcn_fdot2(w3, bc2(a1.w), pa1, false);
            pa2 = __builtin_amdgcn_fdot2(w0, bc2(a2.x), pa2, false);
            pa2 = __builtin_amdgcn_fdot2(w1, bc2(a2.y), pa2, false);
            pa2 = __builtin_amdgcn_fdot2(w2, bc2(a2.z), pa2, false);
            pa2 = __builtin_amdgcn_fdot2(w3, bc2(a2.w), pa2, false);
            pa3 = __builtin_amdgcn_fdot2(w0, bc2(a3.x), pa3, false);
            pa3 = __builtin_amdgcn_fdot2(w1, bc2(a3.y), pa3, false);
            pa3 = __builtin_amdgcn_fdot2(w2, bc2(a3.z), pa3, false);
            pa3 = __builtin_amdgcn_fdot2(w3, bc2(a3.w), pa3, false);
        }
        red_s[0][w][lane] = pa0;
        red_s[1][w][lane] = pa1;
        red_s[2][w][lane] = pa2;
        red_s[3][w][lane] = pa3;
    }
    __syncthreads();   // BARRIER 2: cross-wave red_s

    // ---- wave w finalizes point w ----
    {
        float acc = conv_b[lane]
                  + ((red_s[w][0][lane] + red_s[w][1][lane])
                   + (red_s[w][2][lane] + red_s[w][3][lane]));
        for (int c = 0; c < CIN; ++c)
            acc += fcol_s[w][c] * mowT[c * COUT + lane];
        acc += mob[lane];
        out[(size_t)(b * COUT + lane) * NN + n] = acc;
    }
}

// ---------------------------------------------------------------------------
// BatchNorm per channel over (B,N), fp32 in-place. 64 blocks x 256.
// ---------------------------------------------------------------------------
__global__ __launch_bounds__(256) void bn_kernel(
    float* __restrict__ out,
    const float* __restrict__ gamma,
    const float* __restrict__ beta)
{
    const int o = blockIdx.x;
    __shared__ float s1[256], s2[256];
    __shared__ float mean_s, inv_s;

    float a = 0.0f, q = 0.0f;
    for (int i = threadIdx.x; i < BB * NN; i += 256) {
        int b = i >> 11, n = i & (NN - 1);
        float v = out[(size_t)(b * COUT + o) * NN + n];
        a += v; q += v * v;
    }
    s1[threadIdx.x] = a; s2[threadIdx.x] = q;
    __syncthreads();
    for (int s = 128; s > 0; s >>= 1) {
        if (threadIdx.x < s) {
            s1[threadIdx.x] += s1[threadIdx.x + s];
            s2[threadIdx.x] += s2[threadIdx.x + s];
        }
        __syncthreads();
    }
    if (threadIdx.x == 0) {
        const float M = (float)(BB * NN);
        float mean = s1[0] / M;
        float var  = s2[0] / M - mean * mean;
        if (var < 0.0f) var = 0.0f;
        mean_s = mean;
        inv_s  = 1.0f / sqrtf(var + 1e-5f);
    }
    __syncthreads();
    const float mean = mean_s, inv = inv_s;
    const float g = gamma[o], be = beta[o];
    for (int i = threadIdx.x; i < BB * NN; i += 256) {
        int b = i >> 11, n = i & (NN - 1);
        size_t ad = (size_t)(b * COUT + o) * NN + n;
        out[ad] = (out[ad] - mean) * inv * g + be;
    }
}

// ---------------------------------------------------------------------------
extern "C" void kernel_launch(void* const* d_in, const int* in_sizes, int n_in,
                              void* d_out, int out_size, void* d_ws, size_t ws_size,
                              hipStream_t stream)
{
    const float* x       = (const float*)d_in[0];
    const float* feature = (const float*)d_in[1];
    const float* kern    = (const float*)d_in[2];
    const float* pad     = (const float*)d_in[3];
    const float* mlp_w   = (const float*)d_in[4];
    const float* mlp_b   = (const float*)d_in[5];
    const float* conv_w  = (const float*)d_in[6];
    const float* conv_b  = (const float*)d_in[7];
    const float* mow     = (const float*)d_in[8];
    const float* mob     = (const float*)d_in[9];
    const float* gamma   = (const float*)d_in[10];
    const float* beta    = (const float*)d_in[11];

    char* wsp = (char*)d_ws;
    uint4* wTh  = (uint4*)wsp;                         // 320*64*16 = 327680 B
    float* mowT = (float*)(wsp + 327680);              //  16384 B

    float* out = (float*)d_out;

    prep_kernel<<<(NJ8 * COUT + 255) / 256, 256, 0, stream>>>(conv_w, mow, wTh, mowT);
    point_kernel<<<BB * NN / PPB, 256, 0, stream>>>(x, feature, kern, pad,
                                                    mlp_w, mlp_b, wTh, conv_b,
                                                    mowT, mob, out);
    bn_kernel<<<COUT, 256, 0, stream>>>(out, gamma, beta);
}